// Round 1
// baseline (3146.891 us; speedup 1.0000x reference)
//
#include <hip/hip_runtime.h>

// EdgeNetwork: out[dst] += (ef @ K + b).reshape(4,4) @ node[src], over 16M edges.
// Inputs (setup order): node_features (1M,4) f32, edge_features (16M,3) f32,
// pair_indices (16M,2) int32 (harness passes integers as int32), kernel (3,16) f32,
// bias (16,) f32. Output: (1M,4) f32.

#define EN_NODE_DIM 4

__global__ __launch_bounds__(256) void edge_network_kernel(
    const float* __restrict__ node_features,
    const float* __restrict__ edge_features,
    const int*   __restrict__ pair_indices,
    const float* __restrict__ kmat,   // 48 floats (3 x 16)
    const float* __restrict__ bias,   // 16 floats
    float*       __restrict__ out,    // 1M x 4, pre-zeroed
    int n_edges)
{
    __shared__ float sK[48];
    __shared__ float sB[16];
    if (threadIdx.x < 48) sK[threadIdx.x] = kmat[threadIdx.x];
    if (threadIdx.x < 16) sB[threadIdx.x] = bias[threadIdx.x];
    __syncthreads();

    int e = blockIdx.x * blockDim.x + threadIdx.x;
    const int stride = gridDim.x * blockDim.x;

    for (; e < n_edges; e += stride) {
        // edge features: 3 consecutive floats (12 B/lane, coalesced)
        const float e0 = edge_features[3 * e + 0];
        const float e1 = edge_features[3 * e + 1];
        const float e2 = edge_features[3 * e + 2];

        // pair indices: (src, dst) as int2 (8 B aligned)
        const int2 pi = *reinterpret_cast<const int2*>(&pair_indices[2 * e]);

        // gather source node features: float4 (16 B aligned)
        const float4 s = *reinterpret_cast<const float4*>(&node_features[4 * (long)pi.x]);
        const float sj[4] = { s.x, s.y, s.z, s.w };

        // t[i] = sum_j (e @ K + b)[i*4+j] * src[j]
        float t[4];
        #pragma unroll
        for (int i = 0; i < EN_NODE_DIM; ++i) {
            float acc = 0.0f;
            #pragma unroll
            for (int j = 0; j < EN_NODE_DIM; ++j) {
                const int k = 4 * i + j;
                const float m = e0 * sK[k] + e1 * sK[16 + k] + e2 * sK[32 + k] + sB[k];
                acc += m * sj[j];
            }
            t[i] = acc;
        }

        // scatter-add into destination node
        float* o = &out[4 * (long)pi.y];
        #pragma unroll
        for (int i = 0; i < EN_NODE_DIM; ++i)
            atomicAdd(&o[i], t[i]);
    }
}

extern "C" void kernel_launch(void* const* d_in, const int* in_sizes, int n_in,
                              void* d_out, int out_size, void* d_ws, size_t ws_size,
                              hipStream_t stream) {
    const float* node_features = (const float*)d_in[0];
    const float* edge_features = (const float*)d_in[1];
    const int*   pair_indices  = (const int*)d_in[2];
    const float* kmat          = (const float*)d_in[3];
    const float* bias          = (const float*)d_in[4];
    float*       out           = (float*)d_out;

    const int n_edges = in_sizes[1] / 3;   // 16,000,000

    // zero the output accumulator every call (harness does not re-poison)
    hipMemsetAsync(out, 0, (size_t)out_size * sizeof(float), stream);

    const int block = 256;
    const int grid  = (n_edges + block - 1) / block;  // 62,500 blocks
    edge_network_kernel<<<grid, block, 0, stream>>>(
        node_features, edge_features, pair_indices, kmat, bias, out, n_edges);
}